// Round 10
// baseline (207.436 us; speedup 1.0000x reference)
//
#include <hip/hip_runtime.h>
#include <cstdint>
#include <cstddef>

// Problem constants
#define BB   2
#define SS   1024
#define HID  2048
#define HH   32
#define KVHH 8
#define DD   64
#define NQKV 3072   // fused QKV projection width: 2048 q + 512 k + 512 v
#define QKW  2560   // qk_bf row width: 2048 q + 512 k

typedef __attribute__((ext_vector_type(8))) short bf16x8;
typedef __attribute__((ext_vector_type(4))) float f32x4;
typedef __attribute__((ext_vector_type(4))) unsigned int u32x4;

__device__ __forceinline__ unsigned short f2bf(float f) {
    unsigned int u = __float_as_uint(f);
    unsigned int r = (u + 0x7fffu + ((u >> 16) & 1u)) >> 16;
    return (unsigned short)r;
}

// raw v_exp_f32: D = 2^S0 (inputs are pre-scaled by log2e)
__device__ __forceinline__ float ex2(float x) {
    float r; asm("v_exp_f32 %0, %1" : "=v"(r) : "v"(x)); return r;
}

// async global->LDS 16B (wave-uniform LDS base + lane*16 layout required)
__device__ __forceinline__ void g2l16(const unsigned short* g, unsigned short* l) {
    __builtin_amdgcn_global_load_lds(
        (__attribute__((address_space(1))) void*)(unsigned short*)g,
        (__attribute__((address_space(3))) void*)l,
        16, 0, 0);
}

// ---------------------------------------------------------------------------
// prep (vectorized): z=0..3 weight transpose+convert (64x64 tiles, float4
// reads, ushort4 writes); z=4 hidden fp32->bf16 straight convert.
// Also zeroes the attention work-queue counter (stream-ordered upstream).
// ---------------------------------------------------------------------------
__global__ __launch_bounds__(256) void prep(
    const float* __restrict__ hidden,
    const float* __restrict__ Wq, const float* __restrict__ Wk,
    const float* __restrict__ Wv, const float* __restrict__ Wo,
    unsigned short* __restrict__ hidden_bf,
    unsigned short* __restrict__ WqkvT,
    unsigned short* __restrict__ WoT,
    unsigned int* __restrict__ ctr)
{
    const int z   = blockIdx.z;
    const int tid = threadIdx.x;

    if (z == 4) {   // hidden convert, 2048x2048, 64x64 tile
        if (blockIdx.x == 0 && blockIdx.y == 0 && tid == 0) *ctr = 0u;
        int r0 = blockIdx.y * 64, c0 = blockIdx.x * 64;
        #pragma unroll
        for (int p = 0; p < 4; ++p) {
            int f = tid + p * 256;            // 0..1023
            int row = r0 + (f >> 4), c4 = c0 + (f & 15) * 4;
            float4 v = *(const float4*)&hidden[(size_t)row * 2048 + c4];
            ushort4 o;
            o.x = f2bf(v.x); o.y = f2bf(v.y); o.z = f2bf(v.z); o.w = f2bf(v.w);
            *(ushort4*)&hidden_bf[(size_t)row * 2048 + c4] = o;
        }
        return;
    }

    const float* W;
    unsigned short* Wt;
    int N;
    if (z == 0)      { W = Wq; Wt = WqkvT;                        N = 2048; }
    else if (z == 1) { W = Wk; Wt = WqkvT + (size_t)2048 * 2048;  N = 512;  }
    else if (z == 2) { W = Wv; Wt = WqkvT + (size_t)2560 * 2048;  N = 512;  }
    else             { W = Wo; Wt = WoT;                          N = 2048; }
    if (blockIdx.x * 64 >= N) return;

    // 64x64 transpose tile via LDS, stride 68 (2-way bank alias only)
    __shared__ float t[64][68];
    const int n0 = blockIdx.x * 64, k0 = blockIdx.y * 64;
    #pragma unroll
    for (int p = 0; p < 4; ++p) {
        int f = tid + p * 256;
        int row = f >> 4, c4 = (f & 15) * 4;     // row=k_local, c4=n_local
        float4 v = *(const float4*)&W[(size_t)(k0 + row) * N + n0 + c4];
        t[row][c4 + 0] = v.x; t[row][c4 + 1] = v.y;
        t[row][c4 + 2] = v.z; t[row][c4 + 3] = v.w;
    }
    __syncthreads();
    #pragma unroll
    for (int p = 0; p < 4; ++p) {
        int f = tid + p * 256;
        int nrow = f >> 4, kc4 = (f & 15) * 4;   // output row=n, col=k
        ushort4 o;
        o.x = f2bf(t[kc4 + 0][nrow]);
        o.y = f2bf(t[kc4 + 1][nrow]);
        o.z = f2bf(t[kc4 + 2][nrow]);
        o.w = f2bf(t[kc4 + 3][nrow]);
        *(ushort4*)&Wt[(size_t)(n0 + nrow) * 2048 + k0 + kc4] = o;
    }
}

// ---------------------------------------------------------------------------
// Fused QKV GEMM + rope/V-transpose epilogue. Tile 128(M) x 64(N), BK=64,
// 2-phase double-buffered swizzled global_load_lds staging.
// Grid (48, 16) = 768 blocks = 3/CU uniform. Linear block order (working
// set is L3-fit: XCD swizzle costs ~2% here, removed after r9 A/B).
// q rows scaled by 0.125*log2(e): attention uses raw v_exp_f32 (2^x).
// ---------------------------------------------------------------------------
__global__ __launch_bounds__(256) void gemm_qkv_fused(
    const unsigned short* __restrict__ A,     // hidden_bf [2048][2048]
    const unsigned short* __restrict__ Bt,    // WqkvT [3072][2048]
    unsigned short* __restrict__ qk_bf,       // [2048][2560]
    unsigned short* __restrict__ v_t)         // [1024][1024]
{
    __shared__ __align__(16) char smem[49152];   // 2 x (A 16KB + B 8KB)
    float* Ctf = (float*)smem;                   // [128][65] epilogue alias

    const int tid  = threadIdx.x;
    const int lane = tid & 63;
    const int wave = tid >> 6;
    const int quad = lane >> 4;
    const int l15  = lane & 15;
    const int wm = (wave >> 1) * 64, wn = (wave & 1) * 32;
    const int m0 = blockIdx.y * 128, n0 = blockIdx.x * 64;
    const int K = 2048;

    f32x4 acc[4][2] = {};

#define STAGE_Q(k0s, buf) do {                                                \
    unsigned short* Ad = (unsigned short*)(smem + (buf) * 24576);             \
    unsigned short* Bd = (unsigned short*)(smem + (buf) * 24576 + 16384);     \
    _Pragma("unroll")                                                         \
    for (int p = 0; p < 4; ++p) {                                             \
        int ci = tid + p * 256;                                               \
        int row_ = ci >> 3, sc_ = (ci & 7) ^ (row_ & 7);                      \
        g2l16(&A[(size_t)(m0 + row_) * K + (k0s) + sc_ * 8], Ad + ci * 8);    \
    }                                                                         \
    _Pragma("unroll")                                                         \
    for (int p = 0; p < 2; ++p) {                                             \
        int ci = tid + p * 256;                                               \
        int row_ = ci >> 3, sc_ = (ci & 7) ^ (row_ & 7);                      \
        g2l16(&Bt[(size_t)(n0 + row_) * K + (k0s) + sc_ * 8], Bd + ci * 8);   \
    } } while (0)

    STAGE_Q(0, 0);
    __syncthreads();
    int cur = 0;
    for (int k0 = 0; k0 < K; k0 += 64) {
        if (k0 + 64 < K) STAGE_Q(k0 + 64, cur ^ 1);
        const short* Ab = (const short*)(smem + cur * 24576);
        const short* Bb = (const short*)(smem + cur * 24576 + 16384);

        #pragma unroll
        for (int s = 0; s < 2; ++s) {
            bf16x8 af[4], bfr[2];
            #pragma unroll
            for (int i = 0; i < 4; ++i) {
                int row = wm + i * 16 + l15;
                af[i] = *(const bf16x8*)(Ab + row * 64 +
                        ((((s << 2) | quad) ^ (row & 7)) * 8));
            }
            #pragma unroll
            for (int j = 0; j < 2; ++j) {
                int row = wn + j * 16 + l15;
                bfr[j] = *(const bf16x8*)(Bb + row * 64 +
                        ((((s << 2) | quad) ^ (row & 7)) * 8));
            }
            #pragma unroll
            for (int i = 0; i < 4; ++i)
                #pragma unroll
                for (int j = 0; j < 2; ++j)
                    acc[i][j] = __builtin_amdgcn_mfma_f32_16x16x32_bf16(
                        af[i], bfr[j], acc[i][j], 0, 0, 0);
        }
        __syncthreads();
        cur ^= 1;
    }

    // ---- epilogue: fragments -> Ct[128][65] fp32 (aliases staging) ----
    #pragma unroll
    for (int i = 0; i < 4; ++i)
        #pragma unroll
        for (int j = 0; j < 2; ++j)
            #pragma unroll
            for (int rg = 0; rg < 4; ++rg)
                Ctf[(wm + i * 16 + quad * 4 + rg) * 65 + wn + j * 16 + l15]
                    = acc[i][j][rg];
    __syncthreads();

    const int bx = blockIdx.x;
    const int b  = m0 >> 10;           // batch (tile never straddles)
    const int s0 = m0 & 1023;

    if (bx < 40) {
        // rope q/k: qk_bf col base = bx*64 (q: 0..2047; k: 2048 + (bx-32)*64)
        const int hc = bx * 64;
        // q scaled by 0.125 * log2(e) so attention can use exp2 directly
        const float scale = (bx < 32) ? 0.18033688011112042f : 1.0f;
        #pragma unroll
        for (int p = 0; p < 4; ++p) {
            int idx = tid + p * 256;          // 128 rows x 8 t-groups
            int row = idx >> 3, t0 = (idx & 7) * 4;
            int s = s0 + row;
            ushort4 o1, o2;
            #pragma unroll
            for (int k = 0; k < 4; ++k) {
                int t = t0 + k;
                float x1 = Ctf[row * 65 + t];
                float x2 = Ctf[row * 65 + t + 32];
                float inv = __expf(-(float)t * 0.28782313662425572f);
                float ang = (float)s * inv;
                float c  = __cosf(ang);
                float sn = __sinf(ang);
                ((unsigned short*)&o1)[k] = f2bf((x1 * c - x2 * sn) * scale);
                ((unsigned short*)&o2)[k] = f2bf((x2 * c + x1 * sn) * scale);
            }
            unsigned short* dst = qk_bf + (size_t)(m0 + row) * QKW + hc;
            *(ushort4*)&dst[t0]      = o1;
            *(ushort4*)&dst[t0 + 32] = o2;
        }
    } else {
        // v transpose: v_t[(b*512 + (bx-40)*64 + c)][s0 + srow]
        const int vb = b * 512 + (bx - 40) * 64;
        #pragma unroll
        for (int p = 0; p < 8; ++p) {
            int idx = tid + p * 256;          // 64 c x 32 s-groups
            int c = idx >> 5, srow = (idx & 31) * 4;
            ushort4 o;
            #pragma unroll
            for (int k = 0; k < 4; ++k)
                ((unsigned short*)&o)[k] = f2bf(Ctf[(srow + k) * 65 + c]);
            *(ushort4*)&v_t[(size_t)(vb + c) * 1024 + s0 + srow] = o;
        }
    }
#undef STAGE_Q
}

// ---------------------------------------------------------------------------
// bf16 MFMA GEMM, B-transposed (Wo projection). Tile 128x64, BK=64,
// 2-phase double-buffered swizzled staging. 512 blocks = 2/CU uniform.
// ---------------------------------------------------------------------------
__global__ __launch_bounds__(256) void gemm_bf16_bt(
    const unsigned short* __restrict__ A,
    const unsigned short* __restrict__ Bt,
    float* __restrict__ C, int M, int N, int K)
{
    __shared__ __align__(16) char smem[49152];   // 2 x (A 16KB + B 8KB)

    const int tid  = threadIdx.x;
    const int lane = tid & 63;
    const int wave = tid >> 6;
    const int quad = lane >> 4;
    const int l15  = lane & 15;
    const int wm = (wave >> 1) * 64, wn = (wave & 1) * 32;
    const int m0 = blockIdx.y * 128, n0 = blockIdx.x * 64;

    f32x4 acc[4][2] = {};

#define STAGE_O(k0s, buf) do {                                                \
    unsigned short* Ad = (unsigned short*)(smem + (buf) * 24576);             \
    unsigned short* Bd = (unsigned short*)(smem + (buf) * 24576 + 16384);     \
    _Pragma("unroll")                                                         \
    for (int p = 0; p < 4; ++p) {                                             \
        int ci = tid + p * 256;                                               \
        int row_ = ci >> 3, sc_ = (ci & 7) ^ (row_ & 7);                      \
        g2l16(&A[(size_t)(m0 + row_) * K + (k0s) + sc_ * 8], Ad + ci * 8);    \
    }                                                                         \
    _Pragma("unroll")                                                         \
    for (int p = 0; p < 2; ++p) {                                             \
        int ci = tid + p * 256;                                               \
        int row_ = ci >> 3, sc_ = (ci & 7) ^ (row_ & 7);                      \
        g2l16(&Bt[(size_t)(n0 + row_) * K + (k0s) + sc_ * 8], Bd + ci * 8);   \
    } } while (0)

    STAGE_O(0, 0);
    __syncthreads();
    int cur = 0;
    for (int k0 = 0; k0 < K; k0 += 64) {
        if (k0 + 64 < K) STAGE_O(k0 + 64, cur ^ 1);
        const short* Ab = (const short*)(smem + cur * 24576);
        const short* Bb = (const short*)(smem + cur * 24576 + 16384);

        #pragma unroll
        for (int s = 0; s < 2; ++s) {
            bf16x8 af[4], bfr[2];
            #pragma unroll
            for (int i = 0; i < 4; ++i) {
                int row = wm + i * 16 + l15;
                af[i] = *(const bf16x8*)(Ab + row * 64 +
                        ((((s << 2) | quad) ^ (row & 7)) * 8));
            }
            #pragma unroll
            for (int j = 0; j < 2; ++j) {
                int row = wn + j * 16 + l15;
                bfr[j] = *(const bf16x8*)(Bb + row * 64 +
                        ((((s << 2) | quad) ^ (row & 7)) * 8));
            }
            #pragma unroll
            for (int i = 0; i < 4; ++i)
                #pragma unroll
                for (int j = 0; j < 2; ++j)
                    acc[i][j] = __builtin_amdgcn_mfma_f32_16x16x32_bf16(
                        af[i], bfr[j], acc[i][j], 0, 0, 0);
        }
        __syncthreads();
        cur ^= 1;
    }

    #pragma unroll
    for (int i = 0; i < 4; ++i) {
        int grow = m0 + wm + i * 16 + quad * 4;
        #pragma unroll
        for (int j = 0; j < 2; ++j) {
            int gcol = n0 + wn + j * 16 + l15;
            #pragma unroll
            for (int rg = 0; rg < 4; ++rg)
                C[(size_t)(grow + rg) * N + gcol] = acc[i][j][rg];
        }
    }
#undef STAGE_O
}

// ---------------------------------------------------------------------------
// MFMA flash attention, two-pass (r10): persistent work-queue over the
// verified r7 per-item body. 768 blocks (3/CU resident, 24 waves/CU
// sustained) x 512 threads; each block pulls items (qt,h,b) from a global
// atomic counter, heavy-first (item i -> qt = 15 - i/64): heavies start at
// t=0, light items backfill the tail (work-conserving; surplus blocks that
// find the counter exhausted exit immediately, so correctness does not
// depend on residency). Per item: 8 waves = (w4 = q-subtile, grp = k-half),
// shared dbuf swizzled K/V staging, in-reg P->PV, exp2, setprio on MFMA.
// LDS 36.9KB -> 3 blocks/CU.
// ---------------------------------------------------------------------------
__global__ __launch_bounds__(512, 6) void attn_mfma(
    const unsigned short* __restrict__ qk_bf,   // [2048][2560]
    const unsigned short* __restrict__ v_t,     // [1024][1024]
    const float* __restrict__ bias_diag,
    const float* __restrict__ soff,
    unsigned short* __restrict__ AO,            // [2048][2048] bf16
    unsigned int* __restrict__ ctr)
{
    const int tid  = threadIdx.x;
    const int lane = tid & 63;
    const int wave = tid >> 6;                  // 0..7
    const int grp  = wave >> 2;                 // k-half of each 64-k tile
    const int w4   = wave & 3;                  // q sub-tile
    const int quad = lane >> 4;
    const int l15  = lane & 15;

    __shared__ short Ks[2][4096];   // dbuf [64 k][64 d] bf16, chunk-swizzled
    __shared__ short Vs[2][4096];   // dbuf [64 d][64 k] bf16, chunk-swizzled
    __shared__ float bd_s[1024];    // bias * log2e
    __shared__ float red[2][64];    // lp cross-group exchange
    __shared__ int item_s;
    float* Fred = (float*)&Ks[0][0];   // 64x64 f32 = 16KB, alias (post-loop)

#define STAGE_K(j, buf) do {                                                  \
    int ci = tid;                                                             \
    int row_ = ci >> 3, sc_ = (ci & 7) ^ (row_ & 7);                          \
    g2l16(Kg + (size_t)((j) * 64 + row_) * QKW + sc_ * 8,                     \
          (unsigned short*)&Ks[buf][ci * 8]);                                 \
} while (0)

#define STAGE_V(j, buf) do {                                                  \
    int ci = tid;                                                             \
    int row_ = ci >> 3, sc_ = (ci & 7) ^ (row_ & 7);                          \
    g2l16(Vg + (size_t)row_ * SS + (j) * 64 + sc_ * 8,                        \
          (unsigned short*)&Vs[buf][ci * 8]);                                 \
} while (0)

    for (;;) {
        if (tid == 0) item_s = (int)atomicAdd(ctr, 1u);
        __syncthreads();                        // broadcast + protect LDS reuse
        const int item = item_s;
        if (item >= 1024) break;

        const int qt = 15 - (item >> 6);        // heavy-first
        const int hb = item & 63;
        const int h  = hb & 31;
        const int b  = hb >> 5;
        const int kh = h >> 2;
        const int q0 = qt * 64;

        for (int i = tid; i < 1024; i += 512)
            bd_s[i] = bias_diag[h * 1024 + i] * 1.4426950408889634f;

        const unsigned short* Kg = qk_bf + (size_t)(b * SS) * QKW + 2048 + kh * 64;
        const unsigned short* Vg = v_t + (size_t)(b * 512 + kh * 64) * SS;

        const int qrow = q0 + w4 * 16 + l15;    // this lane's q (S^T column)

        const unsigned short* Qg =
            qk_bf + (size_t)(b * SS + q0 + w4 * 16) * QKW + h * 64;
        bf16x8 qf0 = *(const bf16x8*)(Qg + (size_t)l15 * QKW + quad * 8);
        bf16x8 qf1 = *(const bf16x8*)(Qg + (size_t)l15 * QKW + 32 + quad * 8);

        // ---------------- pass 1: l ----------------
        float lpa[4] = {0.f, 0.f, 0.f, 0.f};
        STAGE_K(0, 0);
        __syncthreads();                        // also covers bd_s
        int cur = 0;
        for (int j = 0; j <= qt; ++j) {
            if (j < qt) STAGE_K(j + 1, cur ^ 1);
            const short* Kb = Ks[cur];
            const bool diag = (j == qt);

            f32x4 acc[2] = {};
            __builtin_amdgcn_s_setprio(1);
            #pragma unroll
            for (int nn = 0; nn < 2; ++nn) {
                int nb = 2 * grp + nn;
                if (diag && nb > w4) continue;
                int row = nb * 16 + l15, sw = row & 7;
                bf16x8 a0 = *(const bf16x8*)(Kb + row * 64 + ((quad ^ sw) * 8));
                bf16x8 a1 = *(const bf16x8*)(Kb + row * 64 + (((quad + 4) ^ sw) * 8));
                acc[nn] = __builtin_amdgcn_mfma_f32_16x16x32_bf16(a0, qf0, acc[nn], 0, 0, 0);
                acc[nn] = __builtin_amdgcn_mfma_f32_16x16x32_bf16(a1, qf1, acc[nn], 0, 0, 0);
            }
            __builtin_amdgcn_s_setprio(0);
            if (!diag) {
                #pragma unroll
                for (int nn = 0; nn < 2; ++nn) {
                    int rel0 = qrow - (j * 64 + (2 * grp + nn) * 16 + quad * 4);
                    #pragma unroll
                    for (int r = 0; r < 4; ++r)
                        lpa[r] += ex2(acc[nn][r] + bd_s[rel0 - r]);
                }
            } else {
                #pragma unroll
                for (int nn = 0; nn < 2; ++nn) {
                    int nb = 2 * grp + nn;
                    if (nb > w4) continue;
                    #pragma unroll
                    for (int r = 0; r < 4; ++r) {
                        int rel = qrow - (j * 64 + nb * 16 + quad * 4 + r);
                        if (rel >= 0) lpa[r] += ex2(acc[nn][r] + bd_s[rel]);
                    }
                }
            }
            __syncthreads();
            cur ^= 1;
        }

        // lp: quad-reduce within wave, then cross-group (k-half) via LDS
        float lp = (lpa[0] + lpa[1]) + (lpa[2] + lpa[3]);
        lp += __shfl_xor(lp, 16, 64);
        lp += __shfl_xor(lp, 32, 64);
        if (quad == 0) red[grp][w4 * 16 + l15] = lp;
        __syncthreads();
        lp = red[0][w4 * 16 + l15] + red[1][w4 * 16 + l15];
        const float invl = 1.f / lp;
        const float cl   = fabsf(soff[h] + 1.f) / (float)(qrow + 1) * lp;

        // ---------------- pass 2: output ----------------
        f32x4 oacc[4] = {};
        STAGE_K(0, 0);
        STAGE_V(0, 0);
        __syncthreads();
        cur = 0;
        for (int j = 0; j <= qt; ++j) {
            if (j < qt) { STAGE_K(j + 1, cur ^ 1); STAGE_V(j + 1, cur ^ 1); }
            const short* Kb = Ks[cur];
            const short* Vb = Vs[cur];
            const bool diag = (j == qt);

            f32x4 acc[2] = {};
            __builtin_amdgcn_s_setprio(1);
            #pragma unroll
            for (int nn = 0; nn < 2; ++nn) {
                int nb = 2 * grp + nn;
                if (diag && nb > w4) continue;
                int row = nb * 16 + l15, sw = row & 7;
                bf16x8 a0 = *(const bf16x8*)(Kb + row * 64 + ((quad ^ sw) * 8));
                bf16x8 a1 = *(const bf16x8*)(Kb + row * 64 + (((quad + 4) ^ sw) * 8));
                acc[nn] = __builtin_amdgcn_mfma_f32_16x16x32_bf16(a0, qf0, acc[nn], 0, 0, 0);
                acc[nn] = __builtin_amdgcn_mfma_f32_16x16x32_bf16(a1, qf1, acc[nn], 0, 0, 0);
            }
            __builtin_amdgcn_s_setprio(0);

            // w = relu(exp2(s' + bias') - cl); full tiles are mask-free
            unsigned int pk[2][2];
            if (!diag) {
                #pragma unroll
                for (int nn = 0; nn < 2; ++nn) {
                    float w[4];
                    int rel0 = qrow - (j * 64 + (2 * grp + nn) * 16 + quad * 4);
                    #pragma unroll
                    for (int r = 0; r < 4; ++r)
                        w[r] = fmaxf(ex2(acc[nn][r] + bd_s[rel0 - r]) - cl, 0.f);
                    asm("v_cvt_pk_bf16_f32 %0, %1, %2" : "=v"(pk[nn][0]) : "v"(w[0]), "v"(w[1]));
                    asm("v_cvt_pk_bf16_f32 %0, %1, %2" : "=v"(pk[nn][1]) : "v"(w[2]), "v"(w[3]));
                }
            } else {
                #pragma unroll
                for (int nn = 0; nn < 2; ++nn) {
                    int nb = 2 * grp + nn;
                    float w[4];
                    #pragma unroll
                    for (int r = 0; r < 4; ++r) {
                        int rel = qrow - (j * 64 + nb * 16 + quad * 4 + r);
                        float e = 0.f;
                        if (rel >= 0)
                            e = fmaxf(ex2(acc[nn][r] + bd_s[rel]) - cl, 0.f);
                        w[r] = e;
                    }
                    asm("v_cvt_pk_bf16_f32 %0, %1, %2" : "=v"(pk[nn][0]) : "v"(w[0]), "v"(w[1]));
                    asm("v_cvt_pk_bf16_f32 %0, %1, %2" : "=v"(pk[nn][1]) : "v"(w[2]), "v"(w[3]));
                }
            }
            unsigned int ppk[2][2];
            #pragma unroll
            for (int nn = 0; nn < 2; ++nn) {
                ppk[nn][0] = __shfl_xor(pk[nn][0], 16, 64);
                ppk[nn][1] = __shfl_xor(pk[nn][1], 16, 64);
            }

            // PV for this group's 32-k half; V chunk cv + 4*grp matches the
            // slot permutation (bijection per 64-tile; sums over k).
            if (!(diag && grp == 1 && w4 < 2)) {     // dead kpos block on diag
                const bool oddq = quad & 1;
                const int  cv   = ((quad & 1) << 1) | (quad >> 1);   // 0,2,1,3
                unsigned int w0 = oddq ? ppk[1][0] : pk[0][0];
                unsigned int w1 = oddq ? ppk[1][1] : pk[0][1];
                unsigned int w2 = oddq ? pk[1][0]  : ppk[0][0];
                unsigned int w3 = oddq ? pk[1][1]  : ppk[0][1];
                u32x4 t; t[0] = w0; t[1] = w1; t[2] = w2; t[3] = w3;
                bf16x8 pf = __builtin_bit_cast(bf16x8, t);
                __builtin_amdgcn_s_setprio(1);
                #pragma unroll
                for (int nd = 0; nd < 4; ++nd) {
                    int rowv = nd * 16 + l15, swv = rowv & 7;
                    bf16x8 vf = *(const bf16x8*)(Vb + rowv * 64 + (((cv + 4 * grp) ^ swv) * 8));
                    oacc[nd] = __builtin_amdgcn_mfma_f32_16x16x32_bf16(pf, vf, oacc[nd], 0, 0, 0);
                }
                __builtin_amdgcn_s_setprio(0);
            }
            __syncthreads();
            cur ^= 1;
        }

        // ---- cross-group oacc reduce (grp1 -> Fred, grp0 adds) + output ----
        if (grp == 1) {
            #pragma unroll
            for (int nd = 0; nd < 4; ++nd)
                #pragma unroll
                for (int r = 0; r < 4; ++r)
                    Fred[(w4 * 16 + quad * 4 + r) * 64 + nd * 16 + l15] = oacc[nd][r];
        }
        __syncthreads();
        if (grp == 0) {
            float invl_r[4];
            #pragma unroll
            for (int r = 0; r < 4; ++r)
                invl_r[r] = __shfl(invl, quad * 4 + r, 64);
            unsigned short* aop =
                AO + (size_t)(b * SS + q0 + w4 * 16 + quad * 4) * 2048 + h * 64 + l15;
            #pragma unroll
            for (int nd = 0; nd < 4; ++nd)
                #pragma unroll
                for (int r = 0; r < 4; ++r) {
                    float o = (oacc[nd][r] +
                               Fred[(w4 * 16 + quad * 4 + r) * 64 + nd * 16 + l15])
                              * invl_r[r];
                    aop[(size_t)r * 2048 + nd * 16] = f2bf(o);
                }
        }
        __syncthreads();   // Fred (alias Ks) reads done before next item
    }
#undef STAGE_K
#undef STAGE_V
}

// ---------------------------------------------------------------------------
extern "C" void kernel_launch(void* const* d_in, const int* in_sizes, int n_in,
                              void* d_out, int out_size, void* d_ws, size_t ws_size,
                              hipStream_t stream)
{
    const float* hidden    = (const float*)d_in[0];
    const float* Wq        = (const float*)d_in[2];
    const float* Wk        = (const float*)d_in[3];
    const float* Wv        = (const float*)d_in[4];
    const float* Wo        = (const float*)d_in[5];
    const float* bias_diag = (const float*)d_in[6];
    const float* soff      = (const float*)d_in[7];
    float* out = (float*)d_out;

    // Workspace aliasing:
    //  A [0,20.97M): hidden_bf(8.39) + WqkvT(12.58) -- inputs of QKV gemm.
    //                AO_bf at [12.58M..) only AFTER WqkvT is dead (attention
    //                writes AO_bf after the QKV gemm consumed WqkvT).
    //  B [20.97M,29.36M): WoT
    //  C [29.36M,41.94M): qk_bf(10.49M) + v_t(2.10M)
    //  D [41.94M): attention work-queue counter (4B, zeroed by prep)
    char* wsb = (char*)d_ws;
    unsigned short* hidden_bf = (unsigned short*)wsb;
    unsigned short* WqkvT     = (unsigned short*)(wsb + (size_t)8388608);
    unsigned short* AO_bf     = (unsigned short*)(wsb + (size_t)12582912);
    unsigned short* WoT       = (unsigned short*)(wsb + (size_t)20971520);
    unsigned short* qk_bf     = (unsigned short*)(wsb + (size_t)29360128);
    unsigned short* v_t       = (unsigned short*)(wsb + (size_t)29360128 + (size_t)2048 * 2560 * 2);
    unsigned int*   ctr       = (unsigned int*)(wsb + (size_t)41943040);

    // 1. weight transposes + hidden convert + counter zero (one launch)
    prep<<<dim3(32, 32, 5), dim3(256), 0, stream>>>(
        hidden, Wq, Wk, Wv, Wo, hidden_bf, WqkvT, WoT, ctr);

    // 2. fused QKV projection + rope/V-transpose epilogue
    //    (768 blocks = 3/CU uniform, 2-phase dbuf pipeline)
    gemm_qkv_fused<<<dim3(48, 16), dim3(256), 0, stream>>>(
        hidden_bf, WqkvT, qk_bf, v_t);

    // 3. persistent work-queue MFMA attention (768 blocks = 3/CU + queue)
    attn_mfma<<<dim3(768), dim3(512), 0, stream>>>(
        qk_bf, v_t, bias_diag, soff, AO_bf, ctr);

    // 4. output projection (512 blocks = 2/CU, 2-phase dbuf pipeline)
    gemm_bf16_bt<<<dim3(2048 / 64, 2048 / 128), dim3(256), 0, stream>>>(
        AO_bf, WoT, out, 2048, 2048, 2048);
}

// Round 11
// 199.928 us; speedup vs baseline: 1.0376x; 1.0376x over previous
//
#include <hip/hip_runtime.h>
#include <cstdint>
#include <cstddef>

// Problem constants
#define BB   2
#define SS   1024
#define HID  2048
#define HH   32
#define KVHH 8
#define DD   64
#define NQKV 3072   // fused QKV projection width: 2048 q + 512 k + 512 v
#define QKW  2560   // qk_bf row width: 2048 q + 512 k

typedef __attribute__((ext_vector_type(8))) short bf16x8;
typedef __attribute__((ext_vector_type(4))) float f32x4;
typedef __attribute__((ext_vector_type(4))) unsigned int u32x4;

__device__ __forceinline__ unsigned short f2bf(float f) {
    unsigned int u = __float_as_uint(f);
    unsigned int r = (u + 0x7fffu + ((u >> 16) & 1u)) >> 16;
    return (unsigned short)r;
}

// raw v_exp_f32: D = 2^S0 (inputs are pre-scaled by log2e)
__device__ __forceinline__ float ex2(float x) {
    float r; asm("v_exp_f32 %0, %1" : "=v"(r) : "v"(x)); return r;
}

// async global->LDS 16B (wave-uniform LDS base + lane*16 layout required)
__device__ __forceinline__ void g2l16(const unsigned short* g, unsigned short* l) {
    __builtin_amdgcn_global_load_lds(
        (__attribute__((address_space(1))) void*)(unsigned short*)g,
        (__attribute__((address_space(3))) void*)l,
        16, 0, 0);
}

// ---------------------------------------------------------------------------
// prep (vectorized): z=0..3 weight transpose+convert (64x64 tiles, float4
// reads, ushort4 writes); z=4 hidden fp32->bf16 straight convert.
// ---------------------------------------------------------------------------
__global__ __launch_bounds__(256) void prep(
    const float* __restrict__ hidden,
    const float* __restrict__ Wq, const float* __restrict__ Wk,
    const float* __restrict__ Wv, const float* __restrict__ Wo,
    unsigned short* __restrict__ hidden_bf,
    unsigned short* __restrict__ WqkvT,
    unsigned short* __restrict__ WoT)
{
    const int z   = blockIdx.z;
    const int tid = threadIdx.x;

    if (z == 4) {   // hidden convert, 2048x2048, 64x64 tile
        int r0 = blockIdx.y * 64, c0 = blockIdx.x * 64;
        #pragma unroll
        for (int p = 0; p < 4; ++p) {
            int f = tid + p * 256;            // 0..1023
            int row = r0 + (f >> 4), c4 = c0 + (f & 15) * 4;
            float4 v = *(const float4*)&hidden[(size_t)row * 2048 + c4];
            ushort4 o;
            o.x = f2bf(v.x); o.y = f2bf(v.y); o.z = f2bf(v.z); o.w = f2bf(v.w);
            *(ushort4*)&hidden_bf[(size_t)row * 2048 + c4] = o;
        }
        return;
    }

    const float* W;
    unsigned short* Wt;
    int N;
    if (z == 0)      { W = Wq; Wt = WqkvT;                        N = 2048; }
    else if (z == 1) { W = Wk; Wt = WqkvT + (size_t)2048 * 2048;  N = 512;  }
    else if (z == 2) { W = Wv; Wt = WqkvT + (size_t)2560 * 2048;  N = 512;  }
    else             { W = Wo; Wt = WoT;                          N = 2048; }
    if (blockIdx.x * 64 >= N) return;

    // 64x64 transpose tile via LDS, stride 68 (2-way bank alias only)
    __shared__ float t[64][68];
    const int n0 = blockIdx.x * 64, k0 = blockIdx.y * 64;
    #pragma unroll
    for (int p = 0; p < 4; ++p) {
        int f = tid + p * 256;
        int row = f >> 4, c4 = (f & 15) * 4;     // row=k_local, c4=n_local
        float4 v = *(const float4*)&W[(size_t)(k0 + row) * N + n0 + c4];
        t[row][c4 + 0] = v.x; t[row][c4 + 1] = v.y;
        t[row][c4 + 2] = v.z; t[row][c4 + 3] = v.w;
    }
    __syncthreads();
    #pragma unroll
    for (int p = 0; p < 4; ++p) {
        int f = tid + p * 256;
        int nrow = f >> 4, kc4 = (f & 15) * 4;   // output row=n, col=k
        ushort4 o;
        o.x = f2bf(t[kc4 + 0][nrow]);
        o.y = f2bf(t[kc4 + 1][nrow]);
        o.z = f2bf(t[kc4 + 2][nrow]);
        o.w = f2bf(t[kc4 + 3][nrow]);
        *(ushort4*)&Wt[(size_t)(n0 + nrow) * 2048 + k0 + kc4] = o;
    }
}

// ---------------------------------------------------------------------------
// Fused QKV GEMM + rope/V-transpose epilogue. Tile 128(M) x 64(N), BK=64,
// 2-phase double-buffered swizzled global_load_lds staging.
// Grid (48, 16) = 768 blocks = 3/CU uniform. Linear block order (working
// set is L3-fit; XCD swizzle measured net-negative here).
// q rows scaled by 0.125*log2(e): attention uses raw v_exp_f32 (2^x).
// ---------------------------------------------------------------------------
__global__ __launch_bounds__(256) void gemm_qkv_fused(
    const unsigned short* __restrict__ A,     // hidden_bf [2048][2048]
    const unsigned short* __restrict__ Bt,    // WqkvT [3072][2048]
    unsigned short* __restrict__ qk_bf,       // [2048][2560]
    unsigned short* __restrict__ v_t)         // [1024][1024]
{
    __shared__ __align__(16) char smem[49152];   // 2 x (A 16KB + B 8KB)
    float* Ctf = (float*)smem;                   // [128][65] epilogue alias

    const int tid  = threadIdx.x;
    const int lane = tid & 63;
    const int wave = tid >> 6;
    const int quad = lane >> 4;
    const int l15  = lane & 15;
    const int wm = (wave >> 1) * 64, wn = (wave & 1) * 32;
    const int m0 = blockIdx.y * 128, n0 = blockIdx.x * 64;
    const int K = 2048;

    f32x4 acc[4][2] = {};

#define STAGE_Q(k0s, buf) do {                                                \
    unsigned short* Ad = (unsigned short*)(smem + (buf) * 24576);             \
    unsigned short* Bd = (unsigned short*)(smem + (buf) * 24576 + 16384);     \
    _Pragma("unroll")                                                         \
    for (int p = 0; p < 4; ++p) {                                             \
        int ci = tid + p * 256;                                               \
        int row_ = ci >> 3, sc_ = (ci & 7) ^ (row_ & 7);                      \
        g2l16(&A[(size_t)(m0 + row_) * K + (k0s) + sc_ * 8], Ad + ci * 8);    \
    }                                                                         \
    _Pragma("unroll")                                                         \
    for (int p = 0; p < 2; ++p) {                                             \
        int ci = tid + p * 256;                                               \
        int row_ = ci >> 3, sc_ = (ci & 7) ^ (row_ & 7);                      \
        g2l16(&Bt[(size_t)(n0 + row_) * K + (k0s) + sc_ * 8], Bd + ci * 8);   \
    } } while (0)

    STAGE_Q(0, 0);
    __syncthreads();
    int cur = 0;
    for (int k0 = 0; k0 < K; k0 += 64) {
        if (k0 + 64 < K) STAGE_Q(k0 + 64, cur ^ 1);
        const short* Ab = (const short*)(smem + cur * 24576);
        const short* Bb = (const short*)(smem + cur * 24576 + 16384);

        #pragma unroll
        for (int s = 0; s < 2; ++s) {
            bf16x8 af[4], bfr[2];
            #pragma unroll
            for (int i = 0; i < 4; ++i) {
                int row = wm + i * 16 + l15;
                af[i] = *(const bf16x8*)(Ab + row * 64 +
                        ((((s << 2) | quad) ^ (row & 7)) * 8));
            }
            #pragma unroll
            for (int j = 0; j < 2; ++j) {
                int row = wn + j * 16 + l15;
                bfr[j] = *(const bf16x8*)(Bb + row * 64 +
                        ((((s << 2) | quad) ^ (row & 7)) * 8));
            }
            #pragma unroll
            for (int i = 0; i < 4; ++i)
                #pragma unroll
                for (int j = 0; j < 2; ++j)
                    acc[i][j] = __builtin_amdgcn_mfma_f32_16x16x32_bf16(
                        af[i], bfr[j], acc[i][j], 0, 0, 0);
        }
        __syncthreads();
        cur ^= 1;
    }

    // ---- epilogue: fragments -> Ct[128][65] fp32 (aliases staging) ----
    #pragma unroll
    for (int i = 0; i < 4; ++i)
        #pragma unroll
        for (int j = 0; j < 2; ++j)
            #pragma unroll
            for (int rg = 0; rg < 4; ++rg)
                Ctf[(wm + i * 16 + quad * 4 + rg) * 65 + wn + j * 16 + l15]
                    = acc[i][j][rg];
    __syncthreads();

    const int bx = blockIdx.x;
    const int b  = m0 >> 10;           // batch (tile never straddles)
    const int s0 = m0 & 1023;

    if (bx < 40) {
        // rope q/k: qk_bf col base = bx*64 (q: 0..2047; k: 2048 + (bx-32)*64)
        const int hc = bx * 64;
        // q scaled by 0.125 * log2(e) so attention can use exp2 directly
        const float scale = (bx < 32) ? 0.18033688011112042f : 1.0f;
        #pragma unroll
        for (int p = 0; p < 4; ++p) {
            int idx = tid + p * 256;          // 128 rows x 8 t-groups
            int row = idx >> 3, t0 = (idx & 7) * 4;
            int s = s0 + row;
            ushort4 o1, o2;
            #pragma unroll
            for (int k = 0; k < 4; ++k) {
                int t = t0 + k;
                float x1 = Ctf[row * 65 + t];
                float x2 = Ctf[row * 65 + t + 32];
                float inv = __expf(-(float)t * 0.28782313662425572f);
                float ang = (float)s * inv;
                float c  = __cosf(ang);
                float sn = __sinf(ang);
                ((unsigned short*)&o1)[k] = f2bf((x1 * c - x2 * sn) * scale);
                ((unsigned short*)&o2)[k] = f2bf((x2 * c + x1 * sn) * scale);
            }
            unsigned short* dst = qk_bf + (size_t)(m0 + row) * QKW + hc;
            *(ushort4*)&dst[t0]      = o1;
            *(ushort4*)&dst[t0 + 32] = o2;
        }
    } else {
        // v transpose: v_t[(b*512 + (bx-40)*64 + c)][s0 + srow]
        const int vb = b * 512 + (bx - 40) * 64;
        #pragma unroll
        for (int p = 0; p < 8; ++p) {
            int idx = tid + p * 256;          // 64 c x 32 s-groups
            int c = idx >> 5, srow = (idx & 31) * 4;
            ushort4 o;
            #pragma unroll
            for (int k = 0; k < 4; ++k)
                ((unsigned short*)&o)[k] = f2bf(Ctf[(srow + k) * 65 + c]);
            *(ushort4*)&v_t[(size_t)(vb + c) * 1024 + s0 + srow] = o;
        }
    }
#undef STAGE_Q
}

// ---------------------------------------------------------------------------
// bf16 MFMA GEMM, B-transposed (Wo projection). Tile 128x64, BK=64,
// 2-phase double-buffered swizzled staging. 512 blocks = 2/CU uniform.
// ---------------------------------------------------------------------------
__global__ __launch_bounds__(256) void gemm_bf16_bt(
    const unsigned short* __restrict__ A,
    const unsigned short* __restrict__ Bt,
    float* __restrict__ C, int M, int N, int K)
{
    __shared__ __align__(16) char smem[49152];   // 2 x (A 16KB + B 8KB)

    const int tid  = threadIdx.x;
    const int lane = tid & 63;
    const int wave = tid >> 6;
    const int quad = lane >> 4;
    const int l15  = lane & 15;
    const int wm = (wave >> 1) * 64, wn = (wave & 1) * 32;
    const int m0 = blockIdx.y * 128, n0 = blockIdx.x * 64;

    f32x4 acc[4][2] = {};

#define STAGE_O(k0s, buf) do {                                                \
    unsigned short* Ad = (unsigned short*)(smem + (buf) * 24576);             \
    unsigned short* Bd = (unsigned short*)(smem + (buf) * 24576 + 16384);     \
    _Pragma("unroll")                                                         \
    for (int p = 0; p < 4; ++p) {                                             \
        int ci = tid + p * 256;                                               \
        int row_ = ci >> 3, sc_ = (ci & 7) ^ (row_ & 7);                      \
        g2l16(&A[(size_t)(m0 + row_) * K + (k0s) + sc_ * 8], Ad + ci * 8);    \
    }                                                                         \
    _Pragma("unroll")                                                         \
    for (int p = 0; p < 2; ++p) {                                             \
        int ci = tid + p * 256;                                               \
        int row_ = ci >> 3, sc_ = (ci & 7) ^ (row_ & 7);                      \
        g2l16(&Bt[(size_t)(n0 + row_) * K + (k0s) + sc_ * 8], Bd + ci * 8);   \
    } } while (0)

    STAGE_O(0, 0);
    __syncthreads();
    int cur = 0;
    for (int k0 = 0; k0 < K; k0 += 64) {
        if (k0 + 64 < K) STAGE_O(k0 + 64, cur ^ 1);
        const short* Ab = (const short*)(smem + cur * 24576);
        const short* Bb = (const short*)(smem + cur * 24576 + 16384);

        #pragma unroll
        for (int s = 0; s < 2; ++s) {
            bf16x8 af[4], bfr[2];
            #pragma unroll
            for (int i = 0; i < 4; ++i) {
                int row = wm + i * 16 + l15;
                af[i] = *(const bf16x8*)(Ab + row * 64 +
                        ((((s << 2) | quad) ^ (row & 7)) * 8));
            }
            #pragma unroll
            for (int j = 0; j < 2; ++j) {
                int row = wn + j * 16 + l15;
                bfr[j] = *(const bf16x8*)(Bb + row * 64 +
                        ((((s << 2) | quad) ^ (row & 7)) * 8));
            }
            #pragma unroll
            for (int i = 0; i < 4; ++i)
                #pragma unroll
                for (int j = 0; j < 2; ++j)
                    acc[i][j] = __builtin_amdgcn_mfma_f32_16x16x32_bf16(
                        af[i], bfr[j], acc[i][j], 0, 0, 0);
        }
        __syncthreads();
        cur ^= 1;
    }

    #pragma unroll
    for (int i = 0; i < 4; ++i) {
        int grow = m0 + wm + i * 16 + quad * 4;
        #pragma unroll
        for (int j = 0; j < 2; ++j) {
            int gcol = n0 + wn + j * 16 + l15;
            #pragma unroll
            for (int rg = 0; rg < 4; ++rg)
                C[(size_t)(grow + rg) * N + gcol] = acc[i][j][rg];
        }
    }
#undef STAGE_O
}

// ---------------------------------------------------------------------------
// MFMA flash attention, two-pass (r7 structure, best-measured; + setprio).
// 1024 blocks x 512 threads; block = one (qt,h,b) with balanced qtab
// placement (each CU's 4 resident blocks have qt summing to 30; heavy
// first). 8 waves = (w4 = q-subtile, grp = k-half of each 64-k tile): all
// waves consume the SAME staged K/V tile -> LDS 36.5KB -> 4 blocks/CU.
// Cross-group combine (l via red, oacc via Fred). exp via raw v_exp_f32
// (2^x): q pre-scaled by 0.125*log2e, bias scaled at LDS fill.
// ---------------------------------------------------------------------------
__global__ __launch_bounds__(512, 8) void attn_mfma(
    const unsigned short* __restrict__ qk_bf,   // [2048][2560]
    const unsigned short* __restrict__ v_t,     // [1024][1024]
    const float* __restrict__ bias_diag,
    const float* __restrict__ soff,
    unsigned short* __restrict__ AO)            // [2048][2048] bf16
{
    static const unsigned char qtab[16] =
        {15, 14, 13, 12, 10, 11, 8, 9, 4, 5, 6, 7, 1, 0, 3, 2};
    const int id = (int)blockIdx.x;             // 1024 blocks
    const int vq = id >> 8;                     // launch round 0..3
    const int c  = id & 255;                    // ~CU index
    const int qt = qtab[(vq << 2) | (c & 3)];
    const int bh = c >> 2;                      // 0..63
    const int h  = bh & 31;
    const int b  = bh >> 5;
    const int kh = h >> 2;
    const int tid  = threadIdx.x;
    const int lane = tid & 63;
    const int wave = tid >> 6;                  // 0..7
    const int grp  = wave >> 2;                 // k-half of each 64-k tile
    const int w4   = wave & 3;                  // q sub-tile
    const int quad = lane >> 4;
    const int l15  = lane & 15;
    const int q0   = qt * 64;

    __shared__ short Ks[2][4096];   // dbuf [64 k][64 d] bf16, chunk-swizzled
    __shared__ short Vs[2][4096];   // dbuf [64 d][64 k] bf16, chunk-swizzled
    __shared__ float bd_s[1024];    // bias * log2e
    __shared__ float red[2][64];    // lp cross-group exchange
    float* Fred = (float*)&Ks[0][0];   // 64x64 f32 = 16KB, alias (post-loop)

    for (int i = tid; i < 1024; i += 512)
        bd_s[i] = bias_diag[h * 1024 + i] * 1.4426950408889634f;

    const unsigned short* Kg = qk_bf + (size_t)(b * SS) * QKW + 2048 + kh * 64;
    const unsigned short* Vg = v_t + (size_t)(b * 512 + kh * 64) * SS;

    const int qrow = q0 + w4 * 16 + l15;        // this lane's q (S^T column)

    const unsigned short* Qg =
        qk_bf + (size_t)(b * SS + q0 + w4 * 16) * QKW + h * 64;
    bf16x8 qf0 = *(const bf16x8*)(Qg + (size_t)l15 * QKW + quad * 8);
    bf16x8 qf1 = *(const bf16x8*)(Qg + (size_t)l15 * QKW + 32 + quad * 8);

// stage one 64x64 bf16 tile (512 x 16B chunks, 1/thread), source-side XOR
// swizzle: LDS chunk (row, c') holds global chunk (row, c'^(row&7))
#define STAGE_K(j, buf) do {                                                  \
    int ci = tid;                                                             \
    int row_ = ci >> 3, sc_ = (ci & 7) ^ (row_ & 7);                          \
    g2l16(Kg + (size_t)((j) * 64 + row_) * QKW + sc_ * 8,                     \
          (unsigned short*)&Ks[buf][ci * 8]);                                 \
} while (0)

#define STAGE_V(j, buf) do {                                                  \
    int ci = tid;                                                             \
    int row_ = ci >> 3, sc_ = (ci & 7) ^ (row_ & 7);                          \
    g2l16(Vg + (size_t)row_ * SS + (j) * 64 + sc_ * 8,                        \
          (unsigned short*)&Vs[buf][ci * 8]);                                 \
} while (0)

    // ---------------- pass 1: l ----------------
    float lpa[4] = {0.f, 0.f, 0.f, 0.f};
    STAGE_K(0, 0);
    __syncthreads();                            // also covers bd_s
    int cur = 0;
    for (int j = 0; j <= qt; ++j) {
        if (j < qt) STAGE_K(j + 1, cur ^ 1);
        const short* Kb = Ks[cur];
        const bool diag = (j == qt);

        f32x4 acc[2] = {};
        __builtin_amdgcn_s_setprio(1);
        #pragma unroll
        for (int nn = 0; nn < 2; ++nn) {
            int nb = 2 * grp + nn;
            if (diag && nb > w4) continue;
            int row = nb * 16 + l15, sw = row & 7;
            bf16x8 a0 = *(const bf16x8*)(Kb + row * 64 + ((quad ^ sw) * 8));
            bf16x8 a1 = *(const bf16x8*)(Kb + row * 64 + (((quad + 4) ^ sw) * 8));
            acc[nn] = __builtin_amdgcn_mfma_f32_16x16x32_bf16(a0, qf0, acc[nn], 0, 0, 0);
            acc[nn] = __builtin_amdgcn_mfma_f32_16x16x32_bf16(a1, qf1, acc[nn], 0, 0, 0);
        }
        __builtin_amdgcn_s_setprio(0);
        if (!diag) {
            #pragma unroll
            for (int nn = 0; nn < 2; ++nn) {
                int rel0 = qrow - (j * 64 + (2 * grp + nn) * 16 + quad * 4);
                #pragma unroll
                for (int r = 0; r < 4; ++r)
                    lpa[r] += ex2(acc[nn][r] + bd_s[rel0 - r]);
            }
        } else {
            #pragma unroll
            for (int nn = 0; nn < 2; ++nn) {
                int nb = 2 * grp + nn;
                if (nb > w4) continue;
                #pragma unroll
                for (int r = 0; r < 4; ++r) {
                    int rel = qrow - (j * 64 + nb * 16 + quad * 4 + r);
                    if (rel >= 0) lpa[r] += ex2(acc[nn][r] + bd_s[rel]);
                }
            }
        }
        __syncthreads();
        cur ^= 1;
    }

    // lp: quad-reduce within wave, then cross-group (k-half) via LDS
    float lp = (lpa[0] + lpa[1]) + (lpa[2] + lpa[3]);
    lp += __shfl_xor(lp, 16, 64);
    lp += __shfl_xor(lp, 32, 64);
    if (quad == 0) red[grp][w4 * 16 + l15] = lp;
    __syncthreads();
    lp = red[0][w4 * 16 + l15] + red[1][w4 * 16 + l15];
    const float invl = 1.f / lp;
    const float cl   = fabsf(soff[h] + 1.f) / (float)(qrow + 1) * lp;

    // ---------------- pass 2: output ----------------
    f32x4 oacc[4] = {};
    STAGE_K(0, 0);
    STAGE_V(0, 0);
    __syncthreads();
    cur = 0;
    for (int j = 0; j <= qt; ++j) {
        if (j < qt) { STAGE_K(j + 1, cur ^ 1); STAGE_V(j + 1, cur ^ 1); }
        const short* Kb = Ks[cur];
        const short* Vb = Vs[cur];
        const bool diag = (j == qt);

        f32x4 acc[2] = {};
        __builtin_amdgcn_s_setprio(1);
        #pragma unroll
        for (int nn = 0; nn < 2; ++nn) {
            int nb = 2 * grp + nn;
            if (diag && nb > w4) continue;
            int row = nb * 16 + l15, sw = row & 7;
            bf16x8 a0 = *(const bf16x8*)(Kb + row * 64 + ((quad ^ sw) * 8));
            bf16x8 a1 = *(const bf16x8*)(Kb + row * 64 + (((quad + 4) ^ sw) * 8));
            acc[nn] = __builtin_amdgcn_mfma_f32_16x16x32_bf16(a0, qf0, acc[nn], 0, 0, 0);
            acc[nn] = __builtin_amdgcn_mfma_f32_16x16x32_bf16(a1, qf1, acc[nn], 0, 0, 0);
        }
        __builtin_amdgcn_s_setprio(0);

        // w = relu(exp2(s' + bias') - cl); full tiles are mask-free
        unsigned int pk[2][2];
        if (!diag) {
            #pragma unroll
            for (int nn = 0; nn < 2; ++nn) {
                float w[4];
                int rel0 = qrow - (j * 64 + (2 * grp + nn) * 16 + quad * 4);
                #pragma unroll
                for (int r = 0; r < 4; ++r)
                    w[r] = fmaxf(ex2(acc[nn][r] + bd_s[rel0 - r]) - cl, 0.f);
                asm("v_cvt_pk_bf16_f32 %0, %1, %2" : "=v"(pk[nn][0]) : "v"(w[0]), "v"(w[1]));
                asm("v_cvt_pk_bf16_f32 %0, %1, %2" : "=v"(pk[nn][1]) : "v"(w[2]), "v"(w[3]));
            }
        } else {
            #pragma unroll
            for (int nn = 0; nn < 2; ++nn) {
                int nb = 2 * grp + nn;
                float w[4];
                #pragma unroll
                for (int r = 0; r < 4; ++r) {
                    int rel = qrow - (j * 64 + nb * 16 + quad * 4 + r);
                    float e = 0.f;
                    if (rel >= 0)
                        e = fmaxf(ex2(acc[nn][r] + bd_s[rel]) - cl, 0.f);
                    w[r] = e;
                }
                asm("v_cvt_pk_bf16_f32 %0, %1, %2" : "=v"(pk[nn][0]) : "v"(w[0]), "v"(w[1]));
                asm("v_cvt_pk_bf16_f32 %0, %1, %2" : "=v"(pk[nn][1]) : "v"(w[2]), "v"(w[3]));
            }
        }
        unsigned int ppk[2][2];
        #pragma unroll
        for (int nn = 0; nn < 2; ++nn) {
            ppk[nn][0] = __shfl_xor(pk[nn][0], 16, 64);
            ppk[nn][1] = __shfl_xor(pk[nn][1], 16, 64);
        }

        // PV for this group's 32-k half; V chunk cv + 4*grp matches the
        // slot permutation (bijection per 64-tile; sums over k).
        if (!(diag && grp == 1 && w4 < 2)) {     // dead kpos block on diag
            const bool oddq = quad & 1;
            const int  cv   = ((quad & 1) << 1) | (quad >> 1);   // 0,2,1,3
            unsigned int w0 = oddq ? ppk[1][0] : pk[0][0];
            unsigned int w1 = oddq ? ppk[1][1] : pk[0][1];
            unsigned int w2 = oddq ? pk[1][0]  : ppk[0][0];
            unsigned int w3 = oddq ? pk[1][1]  : ppk[0][1];
            u32x4 t; t[0] = w0; t[1] = w1; t[2] = w2; t[3] = w3;
            bf16x8 pf = __builtin_bit_cast(bf16x8, t);
            __builtin_amdgcn_s_setprio(1);
            #pragma unroll
            for (int nd = 0; nd < 4; ++nd) {
                int rowv = nd * 16 + l15, swv = rowv & 7;
                bf16x8 vf = *(const bf16x8*)(Vb + rowv * 64 + (((cv + 4 * grp) ^ swv) * 8));
                oacc[nd] = __builtin_amdgcn_mfma_f32_16x16x32_bf16(pf, vf, oacc[nd], 0, 0, 0);
            }
            __builtin_amdgcn_s_setprio(0);
        }
        __syncthreads();
        cur ^= 1;
    }

    // ---- cross-group oacc reduce (grp1 -> Fred, grp0 adds) + output ----
    if (grp == 1) {
        #pragma unroll
        for (int nd = 0; nd < 4; ++nd)
            #pragma unroll
            for (int r = 0; r < 4; ++r)
                Fred[(w4 * 16 + quad * 4 + r) * 64 + nd * 16 + l15] = oacc[nd][r];
    }
    __syncthreads();
    if (grp == 0) {
        float invl_r[4];
        #pragma unroll
        for (int r = 0; r < 4; ++r)
            invl_r[r] = __shfl(invl, quad * 4 + r, 64);
        unsigned short* aop =
            AO + (size_t)(b * SS + q0 + w4 * 16 + quad * 4) * 2048 + h * 64 + l15;
        #pragma unroll
        for (int nd = 0; nd < 4; ++nd)
            #pragma unroll
            for (int r = 0; r < 4; ++r) {
                float o = (oacc[nd][r] +
                           Fred[(w4 * 16 + quad * 4 + r) * 64 + nd * 16 + l15])
                          * invl_r[r];
                aop[(size_t)r * 2048 + nd * 16] = f2bf(o);
            }
    }
#undef STAGE_K
#undef STAGE_V
}

// ---------------------------------------------------------------------------
extern "C" void kernel_launch(void* const* d_in, const int* in_sizes, int n_in,
                              void* d_out, int out_size, void* d_ws, size_t ws_size,
                              hipStream_t stream)
{
    const float* hidden    = (const float*)d_in[0];
    const float* Wq        = (const float*)d_in[2];
    const float* Wk        = (const float*)d_in[3];
    const float* Wv        = (const float*)d_in[4];
    const float* Wo        = (const float*)d_in[5];
    const float* bias_diag = (const float*)d_in[6];
    const float* soff      = (const float*)d_in[7];
    float* out = (float*)d_out;

    // Workspace aliasing:
    //  A [0,20.97M): hidden_bf(8.39) + WqkvT(12.58) -- inputs of QKV gemm.
    //                AO_bf at [12.58M..) only AFTER WqkvT is dead (attention
    //                writes AO_bf after the QKV gemm consumed WqkvT).
    //  B [20.97M,29.36M): WoT
    //  C [29.36M,41.94M): qk_bf(10.49M) + v_t(2.10M)
    char* wsb = (char*)d_ws;
    unsigned short* hidden_bf = (unsigned short*)wsb;
    unsigned short* WqkvT     = (unsigned short*)(wsb + (size_t)8388608);
    unsigned short* AO_bf     = (unsigned short*)(wsb + (size_t)12582912);
    unsigned short* WoT       = (unsigned short*)(wsb + (size_t)20971520);
    unsigned short* qk_bf     = (unsigned short*)(wsb + (size_t)29360128);
    unsigned short* v_t       = (unsigned short*)(wsb + (size_t)29360128 + (size_t)2048 * 2560 * 2);

    // 1. weight transposes + hidden convert (one launch, vectorized)
    prep<<<dim3(32, 32, 5), dim3(256), 0, stream>>>(
        hidden, Wq, Wk, Wv, Wo, hidden_bf, WqkvT, WoT);

    // 2. fused QKV projection + rope/V-transpose epilogue
    //    (768 blocks = 3/CU uniform, 2-phase dbuf pipeline)
    gemm_qkv_fused<<<dim3(48, 16), dim3(256), 0, stream>>>(
        hidden_bf, WqkvT, qk_bf, v_t);

    // 3. two-pass MFMA attention, k-split groups, 1024 blocks = 4/CU
    attn_mfma<<<dim3(1024), dim3(512), 0, stream>>>(
        qk_bf, v_t, bias_diag, soff, AO_bf);

    // 4. output projection (512 blocks = 2/CU, 2-phase dbuf pipeline)
    gemm_bf16_bt<<<dim3(2048 / 64, 2048 / 128), dim3(256), 0, stream>>>(
        AO_bf, WoT, out, 2048, 2048, 2048);
}

// Round 12
// 196.641 us; speedup vs baseline: 1.0549x; 1.0167x over previous
//
#include <hip/hip_runtime.h>
#include <cstdint>
#include <cstddef>

// Problem constants
#define BB   2
#define SS   1024
#define HID  2048
#define HH   32
#define KVHH 8
#define DD   64
#define NQKV 3072   // fused QKV projection width: 2048 q + 512 k + 512 v
#define QKW  2560   // qk_bf row width: 2048 q + 512 k

typedef __attribute__((ext_vector_type(8))) short bf16x8;
typedef __attribute__((ext_vector_type(4))) float f32x4;
typedef __attribute__((ext_vector_type(4))) unsigned int u32x4;

__device__ __forceinline__ unsigned short f2bf(float f) {
    unsigned int u = __float_as_uint(f);
    unsigned int r = (u + 0x7fffu + ((u >> 16) & 1u)) >> 16;
    return (unsigned short)r;
}

// raw v_exp_f32: D = 2^S0 (inputs are pre-scaled by log2e)
__device__ __forceinline__ float ex2(float x) {
    float r; asm("v_exp_f32 %0, %1" : "=v"(r) : "v"(x)); return r;
}

// async global->LDS 16B (wave-uniform LDS base + lane*16 layout required)
__device__ __forceinline__ void g2l16(const unsigned short* g, unsigned short* l) {
    __builtin_amdgcn_global_load_lds(
        (__attribute__((address_space(1))) void*)(unsigned short*)g,
        (__attribute__((address_space(3))) void*)l,
        16, 0, 0);
}

// ---------------------------------------------------------------------------
// prep (vectorized): z=0..3 weight transpose+convert (64x64 tiles, float4
// reads, ushort4 writes); z=4 hidden fp32->bf16 straight convert.
// ---------------------------------------------------------------------------
__global__ __launch_bounds__(256) void prep(
    const float* __restrict__ hidden,
    const float* __restrict__ Wq, const float* __restrict__ Wk,
    const float* __restrict__ Wv, const float* __restrict__ Wo,
    unsigned short* __restrict__ hidden_bf,
    unsigned short* __restrict__ WqkvT,
    unsigned short* __restrict__ WoT)
{
    const int z   = blockIdx.z;
    const int tid = threadIdx.x;

    if (z == 4) {   // hidden convert, 2048x2048, 64x64 tile
        int r0 = blockIdx.y * 64, c0 = blockIdx.x * 64;
        #pragma unroll
        for (int p = 0; p < 4; ++p) {
            int f = tid + p * 256;            // 0..1023
            int row = r0 + (f >> 4), c4 = c0 + (f & 15) * 4;
            float4 v = *(const float4*)&hidden[(size_t)row * 2048 + c4];
            ushort4 o;
            o.x = f2bf(v.x); o.y = f2bf(v.y); o.z = f2bf(v.z); o.w = f2bf(v.w);
            *(ushort4*)&hidden_bf[(size_t)row * 2048 + c4] = o;
        }
        return;
    }

    const float* W;
    unsigned short* Wt;
    int N;
    if (z == 0)      { W = Wq; Wt = WqkvT;                        N = 2048; }
    else if (z == 1) { W = Wk; Wt = WqkvT + (size_t)2048 * 2048;  N = 512;  }
    else if (z == 2) { W = Wv; Wt = WqkvT + (size_t)2560 * 2048;  N = 512;  }
    else             { W = Wo; Wt = WoT;                          N = 2048; }
    if (blockIdx.x * 64 >= N) return;

    // 64x64 transpose tile via LDS, stride 68 (2-way bank alias only)
    __shared__ float t[64][68];
    const int n0 = blockIdx.x * 64, k0 = blockIdx.y * 64;
    #pragma unroll
    for (int p = 0; p < 4; ++p) {
        int f = tid + p * 256;
        int row = f >> 4, c4 = (f & 15) * 4;     // row=k_local, c4=n_local
        float4 v = *(const float4*)&W[(size_t)(k0 + row) * N + n0 + c4];
        t[row][c4 + 0] = v.x; t[row][c4 + 1] = v.y;
        t[row][c4 + 2] = v.z; t[row][c4 + 3] = v.w;
    }
    __syncthreads();
    #pragma unroll
    for (int p = 0; p < 4; ++p) {
        int f = tid + p * 256;
        int nrow = f >> 4, kc4 = (f & 15) * 4;   // output row=n, col=k
        ushort4 o;
        o.x = f2bf(t[kc4 + 0][nrow]);
        o.y = f2bf(t[kc4 + 1][nrow]);
        o.z = f2bf(t[kc4 + 2][nrow]);
        o.w = f2bf(t[kc4 + 3][nrow]);
        *(ushort4*)&Wt[(size_t)(n0 + nrow) * 2048 + k0 + kc4] = o;
    }
}

// ---------------------------------------------------------------------------
// Fused QKV GEMM + rope/V-transpose epilogue. Tile 128(M) x 64(N), BK=64,
// 2-phase double-buffered swizzled global_load_lds staging.
// Grid (48, 16) = 768 blocks = 3/CU uniform. Linear block order (working
// set is L3-fit).
// q rows scaled by 0.125*log2(e): attention uses raw v_exp_f32 (2^x).
// ---------------------------------------------------------------------------
__global__ __launch_bounds__(256) void gemm_qkv_fused(
    const unsigned short* __restrict__ A,     // hidden_bf [2048][2048]
    const unsigned short* __restrict__ Bt,    // WqkvT [3072][2048]
    unsigned short* __restrict__ qk_bf,       // [2048][2560]
    unsigned short* __restrict__ v_t)         // [1024][1024]
{
    __shared__ __align__(16) char smem[49152];   // 2 x (A 16KB + B 8KB)
    float* Ctf = (float*)smem;                   // [128][65] epilogue alias

    const int tid  = threadIdx.x;
    const int lane = tid & 63;
    const int wave = tid >> 6;
    const int quad = lane >> 4;
    const int l15  = lane & 15;
    const int wm = (wave >> 1) * 64, wn = (wave & 1) * 32;
    const int m0 = blockIdx.y * 128, n0 = blockIdx.x * 64;
    const int K = 2048;

    f32x4 acc[4][2] = {};

#define STAGE_Q(k0s, buf) do {                                                \
    unsigned short* Ad = (unsigned short*)(smem + (buf) * 24576);             \
    unsigned short* Bd = (unsigned short*)(smem + (buf) * 24576 + 16384);     \
    _Pragma("unroll")                                                         \
    for (int p = 0; p < 4; ++p) {                                             \
        int ci = tid + p * 256;                                               \
        int row_ = ci >> 3, sc_ = (ci & 7) ^ (row_ & 7);                      \
        g2l16(&A[(size_t)(m0 + row_) * K + (k0s) + sc_ * 8], Ad + ci * 8);    \
    }                                                                         \
    _Pragma("unroll")                                                         \
    for (int p = 0; p < 2; ++p) {                                             \
        int ci = tid + p * 256;                                               \
        int row_ = ci >> 3, sc_ = (ci & 7) ^ (row_ & 7);                      \
        g2l16(&Bt[(size_t)(n0 + row_) * K + (k0s) + sc_ * 8], Bd + ci * 8);   \
    } } while (0)

    STAGE_Q(0, 0);
    __syncthreads();
    int cur = 0;
    for (int k0 = 0; k0 < K; k0 += 64) {
        if (k0 + 64 < K) STAGE_Q(k0 + 64, cur ^ 1);
        const short* Ab = (const short*)(smem + cur * 24576);
        const short* Bb = (const short*)(smem + cur * 24576 + 16384);

        #pragma unroll
        for (int s = 0; s < 2; ++s) {
            bf16x8 af[4], bfr[2];
            #pragma unroll
            for (int i = 0; i < 4; ++i) {
                int row = wm + i * 16 + l15;
                af[i] = *(const bf16x8*)(Ab + row * 64 +
                        ((((s << 2) | quad) ^ (row & 7)) * 8));
            }
            #pragma unroll
            for (int j = 0; j < 2; ++j) {
                int row = wn + j * 16 + l15;
                bfr[j] = *(const bf16x8*)(Bb + row * 64 +
                        ((((s << 2) | quad) ^ (row & 7)) * 8));
            }
            #pragma unroll
            for (int i = 0; i < 4; ++i)
                #pragma unroll
                for (int j = 0; j < 2; ++j)
                    acc[i][j] = __builtin_amdgcn_mfma_f32_16x16x32_bf16(
                        af[i], bfr[j], acc[i][j], 0, 0, 0);
        }
        __syncthreads();
        cur ^= 1;
    }

    // ---- epilogue: fragments -> Ct[128][65] fp32 (aliases staging) ----
    #pragma unroll
    for (int i = 0; i < 4; ++i)
        #pragma unroll
        for (int j = 0; j < 2; ++j)
            #pragma unroll
            for (int rg = 0; rg < 4; ++rg)
                Ctf[(wm + i * 16 + quad * 4 + rg) * 65 + wn + j * 16 + l15]
                    = acc[i][j][rg];
    __syncthreads();

    const int bx = blockIdx.x;
    const int b  = m0 >> 10;           // batch (tile never straddles)
    const int s0 = m0 & 1023;

    if (bx < 40) {
        // rope q/k: qk_bf col base = bx*64 (q: 0..2047; k: 2048 + (bx-32)*64)
        const int hc = bx * 64;
        // q scaled by 0.125 * log2(e) so attention can use exp2 directly
        const float scale = (bx < 32) ? 0.18033688011112042f : 1.0f;
        #pragma unroll
        for (int p = 0; p < 4; ++p) {
            int idx = tid + p * 256;          // 128 rows x 8 t-groups
            int row = idx >> 3, t0 = (idx & 7) * 4;
            int s = s0 + row;
            ushort4 o1, o2;
            #pragma unroll
            for (int k = 0; k < 4; ++k) {
                int t = t0 + k;
                float x1 = Ctf[row * 65 + t];
                float x2 = Ctf[row * 65 + t + 32];
                float inv = __expf(-(float)t * 0.28782313662425572f);
                float ang = (float)s * inv;
                float c  = __cosf(ang);
                float sn = __sinf(ang);
                ((unsigned short*)&o1)[k] = f2bf((x1 * c - x2 * sn) * scale);
                ((unsigned short*)&o2)[k] = f2bf((x2 * c + x1 * sn) * scale);
            }
            unsigned short* dst = qk_bf + (size_t)(m0 + row) * QKW + hc;
            *(ushort4*)&dst[t0]      = o1;
            *(ushort4*)&dst[t0 + 32] = o2;
        }
    } else {
        // v transpose: v_t[(b*512 + (bx-40)*64 + c)][s0 + srow]
        const int vb = b * 512 + (bx - 40) * 64;
        #pragma unroll
        for (int p = 0; p < 8; ++p) {
            int idx = tid + p * 256;          // 64 c x 32 s-groups
            int c = idx >> 5, srow = (idx & 31) * 4;
            ushort4 o;
            #pragma unroll
            for (int k = 0; k < 4; ++k)
                ((unsigned short*)&o)[k] = f2bf(Ctf[(srow + k) * 65 + c]);
            *(ushort4*)&v_t[(size_t)(vb + c) * 1024 + s0 + srow] = o;
        }
    }
#undef STAGE_Q
}

// ---------------------------------------------------------------------------
// bf16 MFMA GEMM, B-transposed (Wo projection). Tile 128x64, BK=64,
// 2-phase double-buffered swizzled staging. 512 blocks = 2/CU uniform.
// ---------------------------------------------------------------------------
__global__ __launch_bounds__(256) void gemm_bf16_bt(
    const unsigned short* __restrict__ A,
    const unsigned short* __restrict__ Bt,
    float* __restrict__ C, int M, int N, int K)
{
    __shared__ __align__(16) char smem[49152];   // 2 x (A 16KB + B 8KB)

    const int tid  = threadIdx.x;
    const int lane = tid & 63;
    const int wave = tid >> 6;
    const int quad = lane >> 4;
    const int l15  = lane & 15;
    const int wm = (wave >> 1) * 64, wn = (wave & 1) * 32;
    const int m0 = blockIdx.y * 128, n0 = blockIdx.x * 64;

    f32x4 acc[4][2] = {};

#define STAGE_O(k0s, buf) do {                                                \
    unsigned short* Ad = (unsigned short*)(smem + (buf) * 24576);             \
    unsigned short* Bd = (unsigned short*)(smem + (buf) * 24576 + 16384);     \
    _Pragma("unroll")                                                         \
    for (int p = 0; p < 4; ++p) {                                             \
        int ci = tid + p * 256;                                               \
        int row_ = ci >> 3, sc_ = (ci & 7) ^ (row_ & 7);                      \
        g2l16(&A[(size_t)(m0 + row_) * K + (k0s) + sc_ * 8], Ad + ci * 8);    \
    }                                                                         \
    _Pragma("unroll")                                                         \
    for (int p = 0; p < 2; ++p) {                                             \
        int ci = tid + p * 256;                                               \
        int row_ = ci >> 3, sc_ = (ci & 7) ^ (row_ & 7);                      \
        g2l16(&Bt[(size_t)(n0 + row_) * K + (k0s) + sc_ * 8], Bd + ci * 8);   \
    } } while (0)

    STAGE_O(0, 0);
    __syncthreads();
    int cur = 0;
    for (int k0 = 0; k0 < K; k0 += 64) {
        if (k0 + 64 < K) STAGE_O(k0 + 64, cur ^ 1);
        const short* Ab = (const short*)(smem + cur * 24576);
        const short* Bb = (const short*)(smem + cur * 24576 + 16384);

        #pragma unroll
        for (int s = 0; s < 2; ++s) {
            bf16x8 af[4], bfr[2];
            #pragma unroll
            for (int i = 0; i < 4; ++i) {
                int row = wm + i * 16 + l15;
                af[i] = *(const bf16x8*)(Ab + row * 64 +
                        ((((s << 2) | quad) ^ (row & 7)) * 8));
            }
            #pragma unroll
            for (int j = 0; j < 2; ++j) {
                int row = wn + j * 16 + l15;
                bfr[j] = *(const bf16x8*)(Bb + row * 64 +
                        ((((s << 2) | quad) ^ (row & 7)) * 8));
            }
            #pragma unroll
            for (int i = 0; i < 4; ++i)
                #pragma unroll
                for (int j = 0; j < 2; ++j)
                    acc[i][j] = __builtin_amdgcn_mfma_f32_16x16x32_bf16(
                        af[i], bfr[j], acc[i][j], 0, 0, 0);
        }
        __syncthreads();
        cur ^= 1;
    }

    #pragma unroll
    for (int i = 0; i < 4; ++i) {
        int grow = m0 + wm + i * 16 + quad * 4;
        #pragma unroll
        for (int j = 0; j < 2; ++j) {
            int gcol = n0 + wn + j * 16 + l15;
            #pragma unroll
            for (int rg = 0; rg < 4; ++rg)
                C[(size_t)(grow + rg) * N + gcol] = acc[i][j][rg];
        }
    }
#undef STAGE_O
}

// ---------------------------------------------------------------------------
// MFMA flash attention, two-pass (exact r7 structure -- best-measured).
// 1024 blocks x 512 threads; block = one (qt,h,b) with balanced qtab
// placement (each CU's 4 resident blocks have qt summing to 30; heavy
// first). 8 waves = (w4 = q-subtile, grp = k-half of each 64-k tile): all
// waves consume the SAME staged K/V tile -> LDS 36.5KB -> 4 blocks/CU.
// Cross-group combine (l via red, oacc via Fred). exp via raw v_exp_f32
// (2^x): q pre-scaled by 0.125*log2e, bias scaled at LDS fill.
// No setprio: waves here are barrier-synced lockstep (m190 regime).
// ---------------------------------------------------------------------------
__global__ __launch_bounds__(512, 8) void attn_mfma(
    const unsigned short* __restrict__ qk_bf,   // [2048][2560]
    const unsigned short* __restrict__ v_t,     // [1024][1024]
    const float* __restrict__ bias_diag,
    const float* __restrict__ soff,
    unsigned short* __restrict__ AO)            // [2048][2048] bf16
{
    static const unsigned char qtab[16] =
        {15, 14, 13, 12, 10, 11, 8, 9, 4, 5, 6, 7, 1, 0, 3, 2};
    const int id = (int)blockIdx.x;             // 1024 blocks
    const int vq = id >> 8;                     // launch round 0..3
    const int c  = id & 255;                    // ~CU index
    const int qt = qtab[(vq << 2) | (c & 3)];
    const int bh = c >> 2;                      // 0..63
    const int h  = bh & 31;
    const int b  = bh >> 5;
    const int kh = h >> 2;
    const int tid  = threadIdx.x;
    const int lane = tid & 63;
    const int wave = tid >> 6;                  // 0..7
    const int grp  = wave >> 2;                 // k-half of each 64-k tile
    const int w4   = wave & 3;                  // q sub-tile
    const int quad = lane >> 4;
    const int l15  = lane & 15;
    const int q0   = qt * 64;

    __shared__ short Ks[2][4096];   // dbuf [64 k][64 d] bf16, chunk-swizzled
    __shared__ short Vs[2][4096];   // dbuf [64 d][64 k] bf16, chunk-swizzled
    __shared__ float bd_s[1024];    // bias * log2e
    __shared__ float red[2][64];    // lp cross-group exchange
    float* Fred = (float*)&Ks[0][0];   // 64x64 f32 = 16KB, alias (post-loop)

    for (int i = tid; i < 1024; i += 512)
        bd_s[i] = bias_diag[h * 1024 + i] * 1.4426950408889634f;

    const unsigned short* Kg = qk_bf + (size_t)(b * SS) * QKW + 2048 + kh * 64;
    const unsigned short* Vg = v_t + (size_t)(b * 512 + kh * 64) * SS;

    const int qrow = q0 + w4 * 16 + l15;        // this lane's q (S^T column)

    const unsigned short* Qg =
        qk_bf + (size_t)(b * SS + q0 + w4 * 16) * QKW + h * 64;
    bf16x8 qf0 = *(const bf16x8*)(Qg + (size_t)l15 * QKW + quad * 8);
    bf16x8 qf1 = *(const bf16x8*)(Qg + (size_t)l15 * QKW + 32 + quad * 8);

// stage one 64x64 bf16 tile (512 x 16B chunks, 1/thread), source-side XOR
// swizzle: LDS chunk (row, c') holds global chunk (row, c'^(row&7))
#define STAGE_K(j, buf) do {                                                  \
    int ci = tid;                                                             \
    int row_ = ci >> 3, sc_ = (ci & 7) ^ (row_ & 7);                          \
    g2l16(Kg + (size_t)((j) * 64 + row_) * QKW + sc_ * 8,                     \
          (unsigned short*)&Ks[buf][ci * 8]);                                 \
} while (0)

#define STAGE_V(j, buf) do {                                                  \
    int ci = tid;                                                             \
    int row_ = ci >> 3, sc_ = (ci & 7) ^ (row_ & 7);                          \
    g2l16(Vg + (size_t)row_ * SS + (j) * 64 + sc_ * 8,                        \
          (unsigned short*)&Vs[buf][ci * 8]);                                 \
} while (0)

    // ---------------- pass 1: l ----------------
    float lpa[4] = {0.f, 0.f, 0.f, 0.f};
    STAGE_K(0, 0);
    __syncthreads();                            // also covers bd_s
    int cur = 0;
    for (int j = 0; j <= qt; ++j) {
        if (j < qt) STAGE_K(j + 1, cur ^ 1);
        const short* Kb = Ks[cur];
        const bool diag = (j == qt);

        f32x4 acc[2] = {};
        #pragma unroll
        for (int nn = 0; nn < 2; ++nn) {
            int nb = 2 * grp + nn;
            if (diag && nb > w4) continue;
            int row = nb * 16 + l15, sw = row & 7;
            bf16x8 a0 = *(const bf16x8*)(Kb + row * 64 + ((quad ^ sw) * 8));
            bf16x8 a1 = *(const bf16x8*)(Kb + row * 64 + (((quad + 4) ^ sw) * 8));
            acc[nn] = __builtin_amdgcn_mfma_f32_16x16x32_bf16(a0, qf0, acc[nn], 0, 0, 0);
            acc[nn] = __builtin_amdgcn_mfma_f32_16x16x32_bf16(a1, qf1, acc[nn], 0, 0, 0);
        }
        if (!diag) {
            #pragma unroll
            for (int nn = 0; nn < 2; ++nn) {
                int rel0 = qrow - (j * 64 + (2 * grp + nn) * 16 + quad * 4);
                #pragma unroll
                for (int r = 0; r < 4; ++r)
                    lpa[r] += ex2(acc[nn][r] + bd_s[rel0 - r]);
            }
        } else {
            #pragma unroll
            for (int nn = 0; nn < 2; ++nn) {
                int nb = 2 * grp + nn;
                if (nb > w4) continue;
                #pragma unroll
                for (int r = 0; r < 4; ++r) {
                    int rel = qrow - (j * 64 + nb * 16 + quad * 4 + r);
                    if (rel >= 0) lpa[r] += ex2(acc[nn][r] + bd_s[rel]);
                }
            }
        }
        __syncthreads();
        cur ^= 1;
    }

    // lp: quad-reduce within wave, then cross-group (k-half) via LDS
    float lp = (lpa[0] + lpa[1]) + (lpa[2] + lpa[3]);
    lp += __shfl_xor(lp, 16, 64);
    lp += __shfl_xor(lp, 32, 64);
    if (quad == 0) red[grp][w4 * 16 + l15] = lp;
    __syncthreads();
    lp = red[0][w4 * 16 + l15] + red[1][w4 * 16 + l15];
    const float invl = 1.f / lp;
    const float cl   = fabsf(soff[h] + 1.f) / (float)(qrow + 1) * lp;

    // ---------------- pass 2: output ----------------
    f32x4 oacc[4] = {};
    STAGE_K(0, 0);
    STAGE_V(0, 0);
    __syncthreads();
    cur = 0;
    for (int j = 0; j <= qt; ++j) {
        if (j < qt) { STAGE_K(j + 1, cur ^ 1); STAGE_V(j + 1, cur ^ 1); }
        const short* Kb = Ks[cur];
        const short* Vb = Vs[cur];
        const bool diag = (j == qt);

        f32x4 acc[2] = {};
        #pragma unroll
        for (int nn = 0; nn < 2; ++nn) {
            int nb = 2 * grp + nn;
            if (diag && nb > w4) continue;
            int row = nb * 16 + l15, sw = row & 7;
            bf16x8 a0 = *(const bf16x8*)(Kb + row * 64 + ((quad ^ sw) * 8));
            bf16x8 a1 = *(const bf16x8*)(Kb + row * 64 + (((quad + 4) ^ sw) * 8));
            acc[nn] = __builtin_amdgcn_mfma_f32_16x16x32_bf16(a0, qf0, acc[nn], 0, 0, 0);
            acc[nn] = __builtin_amdgcn_mfma_f32_16x16x32_bf16(a1, qf1, acc[nn], 0, 0, 0);
        }

        // w = relu(exp2(s' + bias') - cl); full tiles are mask-free
        unsigned int pk[2][2];
        if (!diag) {
            #pragma unroll
            for (int nn = 0; nn < 2; ++nn) {
                float w[4];
                int rel0 = qrow - (j * 64 + (2 * grp + nn) * 16 + quad * 4);
                #pragma unroll
                for (int r = 0; r < 4; ++r)
                    w[r] = fmaxf(ex2(acc[nn][r] + bd_s[rel0 - r]) - cl, 0.f);
                asm("v_cvt_pk_bf16_f32 %0, %1, %2" : "=v"(pk[nn][0]) : "v"(w[0]), "v"(w[1]));
                asm("v_cvt_pk_bf16_f32 %0, %1, %2" : "=v"(pk[nn][1]) : "v"(w[2]), "v"(w[3]));
            }
        } else {
            #pragma unroll
            for (int nn = 0; nn < 2; ++nn) {
                int nb = 2 * grp + nn;
                float w[4];
                #pragma unroll
                for (int r = 0; r < 4; ++r) {
                    int rel = qrow - (j * 64 + nb * 16 + quad * 4 + r);
                    float e = 0.f;
                    if (rel >= 0)
                        e = fmaxf(ex2(acc[nn][r] + bd_s[rel]) - cl, 0.f);
                    w[r] = e;
                }
                asm("v_cvt_pk_bf16_f32 %0, %1, %2" : "=v"(pk[nn][0]) : "v"(w[0]), "v"(w[1]));
                asm("v_cvt_pk_bf16_f32 %0, %1, %2" : "=v"(pk[nn][1]) : "v"(w[2]), "v"(w[3]));
            }
        }
        unsigned int ppk[2][2];
        #pragma unroll
        for (int nn = 0; nn < 2; ++nn) {
            ppk[nn][0] = __shfl_xor(pk[nn][0], 16, 64);
            ppk[nn][1] = __shfl_xor(pk[nn][1], 16, 64);
        }

        // PV for this group's 32-k half; V chunk cv + 4*grp matches the
        // slot permutation (bijection per 64-tile; sums over k).
        if (!(diag && grp == 1 && w4 < 2)) {     // dead kpos block on diag
            const bool oddq = quad & 1;
            const int  cv   = ((quad & 1) << 1) | (quad >> 1);   // 0,2,1,3
            unsigned int w0 = oddq ? ppk[1][0] : pk[0][0];
            unsigned int w1 = oddq ? ppk[1][1] : pk[0][1];
            unsigned int w2 = oddq ? pk[1][0]  : ppk[0][0];
            unsigned int w3 = oddq ? pk[1][1]  : ppk[0][1];
            u32x4 t; t[0] = w0; t[1] = w1; t[2] = w2; t[3] = w3;
            bf16x8 pf = __builtin_bit_cast(bf16x8, t);
            #pragma unroll
            for (int nd = 0; nd < 4; ++nd) {
                int rowv = nd * 16 + l15, swv = rowv & 7;
                bf16x8 vf = *(const bf16x8*)(Vb + rowv * 64 + (((cv + 4 * grp) ^ swv) * 8));
                oacc[nd] = __builtin_amdgcn_mfma_f32_16x16x32_bf16(pf, vf, oacc[nd], 0, 0, 0);
            }
        }
        __syncthreads();
        cur ^= 1;
    }

    // ---- cross-group oacc reduce (grp1 -> Fred, grp0 adds) + output ----
    if (grp == 1) {
        #pragma unroll
        for (int nd = 0; nd < 4; ++nd)
            #pragma unroll
            for (int r = 0; r < 4; ++r)
                Fred[(w4 * 16 + quad * 4 + r) * 64 + nd * 16 + l15] = oacc[nd][r];
    }
    __syncthreads();
    if (grp == 0) {
        float invl_r[4];
        #pragma unroll
        for (int r = 0; r < 4; ++r)
            invl_r[r] = __shfl(invl, quad * 4 + r, 64);
        unsigned short* aop =
            AO + (size_t)(b * SS + q0 + w4 * 16 + quad * 4) * 2048 + h * 64 + l15;
        #pragma unroll
        for (int nd = 0; nd < 4; ++nd)
            #pragma unroll
            for (int r = 0; r < 4; ++r) {
                float o = (oacc[nd][r] +
                           Fred[(w4 * 16 + quad * 4 + r) * 64 + nd * 16 + l15])
                          * invl_r[r];
                aop[(size_t)r * 2048 + nd * 16] = f2bf(o);
            }
    }
#undef STAGE_K
#undef STAGE_V
}

// ---------------------------------------------------------------------------
extern "C" void kernel_launch(void* const* d_in, const int* in_sizes, int n_in,
                              void* d_out, int out_size, void* d_ws, size_t ws_size,
                              hipStream_t stream)
{
    const float* hidden    = (const float*)d_in[0];
    const float* Wq        = (const float*)d_in[2];
    const float* Wk        = (const float*)d_in[3];
    const float* Wv        = (const float*)d_in[4];
    const float* Wo        = (const float*)d_in[5];
    const float* bias_diag = (const float*)d_in[6];
    const float* soff      = (const float*)d_in[7];
    float* out = (float*)d_out;

    // Workspace aliasing:
    //  A [0,20.97M): hidden_bf(8.39) + WqkvT(12.58) -- inputs of QKV gemm.
    //                AO_bf at [12.58M..) only AFTER WqkvT is dead (attention
    //                writes AO_bf after the QKV gemm consumed WqkvT).
    //  B [20.97M,29.36M): WoT
    //  C [29.36M,41.94M): qk_bf(10.49M) + v_t(2.10M)
    char* wsb = (char*)d_ws;
    unsigned short* hidden_bf = (unsigned short*)wsb;
    unsigned short* WqkvT     = (unsigned short*)(wsb + (size_t)8388608);
    unsigned short* AO_bf     = (unsigned short*)(wsb + (size_t)12582912);
    unsigned short* WoT       = (unsigned short*)(wsb + (size_t)20971520);
    unsigned short* qk_bf     = (unsigned short*)(wsb + (size_t)29360128);
    unsigned short* v_t       = (unsigned short*)(wsb + (size_t)29360128 + (size_t)2048 * 2560 * 2);

    // 1. weight transposes + hidden convert (one launch, vectorized)
    prep<<<dim3(32, 32, 5), dim3(256), 0, stream>>>(
        hidden, Wq, Wk, Wv, Wo, hidden_bf, WqkvT, WoT);

    // 2. fused QKV projection + rope/V-transpose epilogue
    //    (768 blocks = 3/CU uniform, 2-phase dbuf pipeline)
    gemm_qkv_fused<<<dim3(48, 16), dim3(256), 0, stream>>>(
        hidden_bf, WqkvT, qk_bf, v_t);

    // 3. two-pass MFMA attention, k-split groups, 1024 blocks = 4/CU
    attn_mfma<<<dim3(1024), dim3(512), 0, stream>>>(
        qk_bf, v_t, bias_diag, soff, AO_bf);

    // 4. output projection (512 blocks = 2/CU, 2-phase dbuf pipeline)
    gemm_bf16_bt<<<dim3(2048 / 64, 2048 / 128), dim3(256), 0, stream>>>(
        AO_bf, WoT, out, 2048, 2048, 2048);
}